// Round 1
// baseline (153.341 us; speedup 1.0000x reference)
//
#include <hip/hip_runtime.h>
#include <hip/hip_bf16.h>

#define Bc 32
#define Nc 256
#define Ec 768
#define Hc 12
#define Dc 64
#define Mc 8192   // Bc*Nc

typedef __attribute__((ext_vector_type(8))) __bf16 bf16x8;
typedef __attribute__((ext_vector_type(8))) unsigned short u16x8;
typedef __attribute__((ext_vector_type(4))) float f32x4;

__device__ __forceinline__ unsigned short f2bf(float x) {
  union { float f; unsigned u; } v; v.f = x;
  unsigned r = v.u + 0x7fff + ((v.u >> 16) & 1);   // RNE
  return (unsigned short)(r >> 16);
}

// ---------- prep: query fp32 -> bf16 ----------
__global__ void k_convert_x(const float* __restrict__ X, unsigned short* __restrict__ Xb) {
  int i = (blockIdx.x * 256 + threadIdx.x) * 8;   // grid covers exactly 8192*768
  float4 v0 = *(const float4*)(X + i);
  float4 v1 = *(const float4*)(X + i + 4);
  u16x8 pk;
  pk[0] = f2bf(v0.x); pk[1] = f2bf(v0.y); pk[2] = f2bf(v0.z); pk[3] = f2bf(v0.w);
  pk[4] = f2bf(v1.x); pk[5] = f2bf(v1.y); pk[6] = f2bf(v1.z); pk[7] = f2bf(v1.w);
  *(u16x8*)(Xb + i) = pk;
}

// ---------- prep: WT[n][k] = bf16(scale * W[k][n]); bb[n] ----------
__global__ void k_build_wt(const float* __restrict__ Wq, const float* __restrict__ bq,
                           const float* __restrict__ Wk, const float* __restrict__ bk,
                           unsigned short* __restrict__ WT, float* __restrict__ bb) {
  int n = blockIdx.x;                  // 0..1535
  const float* W; float scale; int col;
  if (n < Ec) { W = Wq; scale = 0.125f; col = n; }
  else        { W = Wk; scale = 1.0f;  col = n - Ec; }
  for (int k = threadIdx.x; k < Ec; k += 256)
    WT[n * Ec + k] = f2bf(scale * W[k * Ec + col]);
  if (threadIdx.x == 0)
    bb[n] = (n < Ec) ? 0.125f * bq[col] : bk[col];
}

// ---------- prep: Wvf[e][h] = sum_d Wv[e][h*64+d]*wf[h*64+d]; bvf ----------
__global__ void k_build_wvf(const float* __restrict__ Wv, const float* __restrict__ bv,
                            const float* __restrict__ wf, float* __restrict__ Wvf,
                            float* __restrict__ bvf) {
  int idx = blockIdx.x * 256 + threadIdx.x;
  if (idx < Ec * Hc) {
    int e = idx / Hc, h = idx % Hc;
    float s = 0.f;
    for (int d = 0; d < Dc; ++d) s += Wv[e * Ec + h * Dc + d] * wf[h * Dc + d];
    Wvf[idx] = s;
  }
  if (idx < Hc) {
    float s = 0.f;
    for (int d = 0; d < Dc; ++d) s += bv[idx * Dc + d] * wf[idx * Dc + d];
    bvf[idx] = s;
  }
}

// ---------- vfT[(b*12+h)*256+m] = query row . Wvf col + bvf ----------
__global__ __launch_bounds__(256) void k_vf(const float* __restrict__ query,
                                            const float* __restrict__ Wvf,
                                            const float* __restrict__ bvf,
                                            float* __restrict__ vfT) {
  __shared__ float wl[Ec * 13];   // padded [768][13] to kill bank conflicts
  __shared__ float bl[Hc];
  for (int i = threadIdx.x; i < Ec * Hc; i += 256) {
    int e = i / Hc, h = i % Hc;
    wl[e * 13 + h] = Wvf[i];
  }
  if (threadIdx.x < Hc) bl[threadIdx.x] = bvf[threadIdx.x];
  __syncthreads();
  int warp = threadIdx.x >> 6, lane = threadIdx.x & 63;
  int r = blockIdx.x * 4 + warp;          // 0..8191
  float q[12];
  #pragma unroll
  for (int i = 0; i < 12; ++i) q[i] = query[r * Ec + lane + 64 * i];
  int b = r >> 8, m = r & 255;
  for (int h = 0; h < Hc; ++h) {
    float s = 0.f;
    #pragma unroll
    for (int i = 0; i < 12; ++i) s += q[i] * wl[(lane + 64 * i) * 13 + h];
    #pragma unroll
    for (int off = 32; off; off >>= 1) s += __shfl_xor(s, off);
    if (lane == 0) vfT[(b * Hc + h) * Nc + m] = s + bl[h];
  }
}

// ---------- GEMM: QK[8192][1536] = Xbf @ WT^T + bb  (bf16 MFMA 16x16x32) ----------
__global__ __launch_bounds__(256) void k_gemm_qk(const unsigned short* __restrict__ Xb,
                                                 const unsigned short* __restrict__ WT,
                                                 const float* __restrict__ bb,
                                                 unsigned short* __restrict__ QK) {
  __shared__ unsigned short As[128][40];   // pad 40: conflict-free b128 reads
  __shared__ unsigned short Bs[128][40];
  int bm = blockIdx.x, bn = blockIdx.y;    // (64, 12)
  int t = threadIdx.x;
  int wave = t >> 6, lane = t & 63;
  int wr = wave >> 1, wc = wave & 1;       // 2x2 wave grid, 64x64 per wave
  int lrow = lane & 15, lk = (lane >> 4) << 3;
  int ar = t >> 2, ac = (t & 3) << 3;
  const int row0 = bm * 128, col0 = bn * 128;

  f32x4 acc[4][4];
  #pragma unroll
  for (int m = 0; m < 4; ++m)
    #pragma unroll
    for (int n = 0; n < 4; ++n) acc[m][n] = f32x4{0.f, 0.f, 0.f, 0.f};

  for (int ks = 0; ks < Ec; ks += 32) {
    #pragma unroll
    for (int rr = ar; rr < 128; rr += 64)
      *(u16x8*)&As[rr][ac] = *(const u16x8*)(Xb + (row0 + rr) * Ec + ks + ac);
    #pragma unroll
    for (int rr = ar; rr < 128; rr += 64)
      *(u16x8*)&Bs[rr][ac] = *(const u16x8*)(WT + (col0 + rr) * Ec + ks + ac);
    __syncthreads();
    bf16x8 af[4], bfg[4];
    #pragma unroll
    for (int m = 0; m < 4; ++m) af[m]  = *(const bf16x8*)&As[wr * 64 + m * 16 + lrow][lk];
    #pragma unroll
    for (int n = 0; n < 4; ++n) bfg[n] = *(const bf16x8*)&Bs[wc * 64 + n * 16 + lrow][lk];
    #pragma unroll
    for (int m = 0; m < 4; ++m)
      #pragma unroll
      for (int n = 0; n < 4; ++n)
        acc[m][n] = __builtin_amdgcn_mfma_f32_16x16x32_bf16(af[m], bfg[n], acc[m][n], 0, 0, 0);
    __syncthreads();
  }
  int crow = (lane >> 4) * 4, ccol = lane & 15;
  #pragma unroll
  for (int m = 0; m < 4; ++m)
    #pragma unroll
    for (int n = 0; n < 4; ++n) {
      int col = col0 + wc * 64 + n * 16 + ccol;
      float bias = bb[col];
      #pragma unroll
      for (int j = 0; j < 4; ++j) {
        int row = row0 + wr * 64 + m * 16 + crow + j;
        QK[row * 1536 + col] = f2bf(acc[m][n][j] + bias);
      }
    }
}

// ---------- fused attention: scores+bias -> softmax -> w -> force ----------
__global__ __launch_bounds__(256) void k_attn(const unsigned short* __restrict__ QK,
                                              const float* __restrict__ bias,
                                              const float* __restrict__ vfT,
                                              const float* __restrict__ delta,
                                              float* __restrict__ out) {
  __shared__ float S[32][260];    // pad 260: 16B-aligned rows, ~2-way banks
  __shared__ float vfl[256];

  int bi = blockIdx.x;
  int xcd = bi & 7, slot = bi >> 3;           // XCD swizzle: same b -> same XCD
  int b = xcd * 4 + (slot >> 3);
  int t0 = (slot & 7) * 32;

  int t = threadIdx.x;
  int wave = t >> 6, lane = t & 63;
  int lrow = lane & 15, lk8 = (lane >> 4) << 3;
  int srow = t >> 3, sl = t & 7;              // softmax: 8 lanes per row

  float w_reg[32];
  #pragma unroll
  for (int i = 0; i < 32; ++i) w_reg[i] = 0.f;

  const int qrow0 = b * Nc + t0;
  for (int h = 0; h < Hc; ++h) {
    __syncthreads();                          // prev head done reading S/vfl
    vfl[t] = vfT[(b * Hc + h) * Nc + t];
    // issue bias tile loads (32x256 f32, fully coalesced)
    float4 breg[8];
    const float* bptr = bias + ((b * Hc + h) * Nc + t0) * Nc;
    #pragma unroll
    for (int i = 0; i < 8; ++i) breg[i] = *(const float4*)(bptr + i * 1024 + t * 4);
    // S = q @ K^T for this head (each wave owns 64 key-columns)
    f32x4 acc[2][4];
    #pragma unroll
    for (int m = 0; m < 2; ++m)
      #pragma unroll
      for (int n = 0; n < 4; ++n) acc[m][n] = f32x4{0.f, 0.f, 0.f, 0.f};
    bf16x8 afr[2][2], bfr[4][2];
    #pragma unroll
    for (int m = 0; m < 2; ++m)
      #pragma unroll
      for (int kk = 0; kk < 2; ++kk)
        afr[m][kk] = *(const bf16x8*)(QK + (qrow0 + m * 16 + lrow) * 1536 + h * 64 + kk * 32 + lk8);
    #pragma unroll
    for (int n = 0; n < 4; ++n)
      #pragma unroll
      for (int kk = 0; kk < 2; ++kk)
        bfr[n][kk] = *(const bf16x8*)(QK + (b * Nc + wave * 64 + n * 16 + lrow) * 1536 + 768 + h * 64 + kk * 32 + lk8);
    #pragma unroll
    for (int m = 0; m < 2; ++m)
      #pragma unroll
      for (int n = 0; n < 4; ++n)
        #pragma unroll
        for (int kk = 0; kk < 2; ++kk)
          acc[m][n] = __builtin_amdgcn_mfma_f32_16x16x32_bf16(afr[m][kk], bfr[n][kk], acc[m][n], 0, 0, 0);
    // bias -> S
    #pragma unroll
    for (int i = 0; i < 8; ++i) {
      int flat = i * 1024 + t * 4;
      *(float4*)&S[flat >> 8][flat & 255] = breg[i];
    }
    __syncthreads();
    // add scores into S (each lane owns distinct (row,col))
    #pragma unroll
    for (int m = 0; m < 2; ++m)
      #pragma unroll
      for (int n = 0; n < 4; ++n) {
        int col = wave * 64 + n * 16 + (lane & 15);
        #pragma unroll
        for (int j = 0; j < 4; ++j)
          S[m * 16 + (lane >> 4) * 4 + j][col] += acc[m][n][j];
      }
    __syncthreads();
    // row softmax (8 lanes/row) + accumulate w in registers
    float sv[32];
    float mx = -1e30f;
    #pragma unroll
    for (int i = 0; i < 32; ++i) { sv[i] = S[srow][sl + 8 * i]; mx = fmaxf(mx, sv[i]); }
    mx = fmaxf(mx, __shfl_xor(mx, 1));
    mx = fmaxf(mx, __shfl_xor(mx, 2));
    mx = fmaxf(mx, __shfl_xor(mx, 4));
    float sum = 0.f;
    #pragma unroll
    for (int i = 0; i < 32; ++i) { sv[i] = __expf(sv[i] - mx); sum += sv[i]; }
    sum += __shfl_xor(sum, 1);
    sum += __shfl_xor(sum, 2);
    sum += __shfl_xor(sum, 4);
    float inv = 1.f / sum;
    #pragma unroll
    for (int i = 0; i < 32; ++i) w_reg[i] += sv[i] * inv * vfl[sl + 8 * i];
  }
  // force[b, t0+srow, c] = sum_m w[m] * delta[b, t0+srow, m, c]
  float f0 = 0.f, f1 = 0.f, f2 = 0.f;
  const float* dp = delta + (size_t)(b * Nc + t0 + srow) * Nc * 3;
  #pragma unroll
  for (int i = 0; i < 32; ++i) {
    int m = sl + 8 * i;
    f0 += w_reg[i] * dp[m * 3 + 0];
    f1 += w_reg[i] * dp[m * 3 + 1];
    f2 += w_reg[i] * dp[m * 3 + 2];
  }
  f0 += __shfl_xor(f0, 1); f0 += __shfl_xor(f0, 2); f0 += __shfl_xor(f0, 4);
  f1 += __shfl_xor(f1, 1); f1 += __shfl_xor(f1, 2); f1 += __shfl_xor(f1, 4);
  f2 += __shfl_xor(f2, 1); f2 += __shfl_xor(f2, 2); f2 += __shfl_xor(f2, 4);
  if (sl == 0) {
    float* o = out + (size_t)(b * Nc + t0 + srow) * 3;
    o[0] = f0; o[1] = f1; o[2] = f2;
  }
}

extern "C" void kernel_launch(void* const* d_in, const int* in_sizes, int n_in,
                              void* d_out, int out_size, void* d_ws, size_t ws_size,
                              hipStream_t stream) {
  const float* query = (const float*)d_in[0];
  const float* attn_bias = (const float*)d_in[1];
  const float* delta_pos = (const float*)d_in[2];
  const float* Wq = (const float*)d_in[3];
  const float* bq = (const float*)d_in[4];
  const float* Wk = (const float*)d_in[5];
  const float* bk = (const float*)d_in[6];
  const float* Wv = (const float*)d_in[7];
  const float* bv = (const float*)d_in[8];
  const float* wf = (const float*)d_in[9];
  float* out = (float*)d_out;

  char* ws = (char*)d_ws;
  unsigned short* WT  = (unsigned short*)(ws);                      // 2,359,296 B
  unsigned short* QKb = (unsigned short*)(ws + 2359296);            // 25,165,824 B
  unsigned short* Xb  = (unsigned short*)(ws + 27525120);           // 12,582,912 B
  float* vfT = (float*)(ws + 40108032);                             // 393,216 B
  float* Wvf = (float*)(ws + 40501248);                             // 36,864 B
  float* bvf = (float*)(ws + 40538112);                             // 48 B
  float* bb  = (float*)(ws + 40538160);                             // 6,144 B

  k_convert_x<<<3072, 256, 0, stream>>>(query, Xb);
  k_build_wt<<<1536, 256, 0, stream>>>(Wq, bq, Wk, bk, WT, bb);
  k_build_wvf<<<36, 256, 0, stream>>>(Wv, bv, wf, Wvf, bvf);
  k_vf<<<2048, 256, 0, stream>>>(query, Wvf, bvf, vfT);
  k_gemm_qk<<<dim3(64, 12), 256, 0, stream>>>(Xb, WT, bb, QKb);
  k_attn<<<256, 256, 0, stream>>>(QKb, attn_bias, vfT, delta_pos, out);
}

// Round 3
// 148.982 us; speedup vs baseline: 1.0293x; 1.0293x over previous
//
#include <hip/hip_runtime.h>
#include <hip/hip_bf16.h>

#define Bc 32
#define Nc 256
#define Ec 768
#define Hc 12
#define Dc 64

typedef __attribute__((ext_vector_type(8))) __bf16 bf16x8;
typedef __attribute__((ext_vector_type(8))) unsigned short u16x8;
typedef __attribute__((ext_vector_type(4))) float f32x4;

__device__ __forceinline__ unsigned short f2bf(float x) {
  union { float f; unsigned u; } v; v.f = x;
  unsigned r = v.u + 0x7fff + ((v.u >> 16) & 1);   // RNE
  return (unsigned short)(r >> 16);
}

#define GL2LDS(gp, lp) __builtin_amdgcn_global_load_lds( \
    (__attribute__((address_space(1))) void*)(gp),        \
    (__attribute__((address_space(3))) void*)(lp), 16, 0, 0)

// ---------- prep: WT[n][k] = bf16(scale*W[k][n]) via LDS tile transpose ----------
__global__ __launch_bounds__(256) void k_trans(const float* __restrict__ Wq,
                                               const float* __restrict__ Wk,
                                               unsigned short* __restrict__ WT) {
  __shared__ float tile[32][33];
  const float* W = blockIdx.z ? Wk : Wq;
  float scale = blockIdx.z ? 1.0f : 0.125f;
  int rowoff = blockIdx.z ? Ec : 0;
  int k0 = blockIdx.x * 32, n0 = blockIdx.y * 32;
  int r = threadIdx.x >> 5, c = threadIdx.x & 31;
  #pragma unroll
  for (int it = 0; it < 4; ++it)
    tile[r + 8 * it][c] = W[(k0 + r + 8 * it) * Ec + n0 + c];
  __syncthreads();
  #pragma unroll
  for (int it = 0; it < 4; ++it)
    WT[(rowoff + n0 + r + 8 * it) * Ec + k0 + c] = f2bf(scale * tile[c][r + 8 * it]);
}

// ---------- prep: Wvf[e][h] = sum_d Wv[e][h*64+d]*wf[.]; bvf; bb ----------
__global__ void k_build_wvf(const float* __restrict__ Wv, const float* __restrict__ bv,
                            const float* __restrict__ wf,
                            const float* __restrict__ bq, const float* __restrict__ bk,
                            float* __restrict__ Wvf, float* __restrict__ bvf,
                            float* __restrict__ bb) {
  int idx = blockIdx.x * 256 + threadIdx.x;
  if (idx < Ec * Hc) {
    int e = idx / Hc, h = idx % Hc;
    float s = 0.f;
    for (int d = 0; d < Dc; ++d) s += Wv[e * Ec + h * Dc + d] * wf[h * Dc + d];
    Wvf[idx] = s;
  }
  if (idx < Hc) {
    float s = 0.f;
    for (int d = 0; d < Dc; ++d) s += bv[idx * Dc + d] * wf[idx * Dc + d];
    bvf[idx] = s;
  }
  if (idx < 2 * Ec)
    bb[idx] = (idx < Ec) ? 0.125f * bq[idx] : bk[idx - Ec];
}

// ---------- vfT + fused query->bf16 conversion ----------
__global__ __launch_bounds__(256) void k_vf(const float* __restrict__ query,
                                            const float* __restrict__ Wvf,
                                            const float* __restrict__ bvf,
                                            float* __restrict__ vfT,
                                            unsigned short* __restrict__ Xb) {
  __shared__ float wl[Ec * 13];
  __shared__ float bl[Hc];
  for (int i = threadIdx.x; i < Ec * Hc; i += 256) {
    int e = i / Hc, h = i % Hc;
    wl[e * 13 + h] = Wvf[i];
  }
  if (threadIdx.x < Hc) bl[threadIdx.x] = bvf[threadIdx.x];
  __syncthreads();
  int warp = threadIdx.x >> 6, lane = threadIdx.x & 63;
  int r = blockIdx.x * 4 + warp;
  float q[12];
  #pragma unroll
  for (int i = 0; i < 12; ++i) q[i] = query[r * Ec + lane + 64 * i];
  #pragma unroll
  for (int i = 0; i < 12; ++i) Xb[r * Ec + lane + 64 * i] = f2bf(q[i]);
  int b = r >> 8, m = r & 255;
  for (int h = 0; h < Hc; ++h) {
    float s = 0.f;
    #pragma unroll
    for (int i = 0; i < 12; ++i) s += q[i] * wl[(lane + 64 * i) * 13 + h];
    #pragma unroll
    for (int off = 32; off; off >>= 1) s += __shfl_xor(s, off);
    if (lane == 0) vfT[(b * Hc + h) * Nc + m] = s + bl[h];
  }
}

// ---------- GEMM (m97 structure): QK[8192][1536] = Xb @ WT^T + bb ----------
__global__ __launch_bounds__(256) void k_gemm_qk(const unsigned short* __restrict__ Xb,
                                                 const unsigned short* __restrict__ WT,
                                                 const float* __restrict__ bb,
                                                 unsigned short* __restrict__ QK) {
  __shared__ unsigned short As[128 * 64];   // linear, XOR octet swizzle
  __shared__ unsigned short Bs[128 * 64];
  int bm = blockIdx.x, bn = blockIdx.y;
  int t = threadIdx.x;
  int wave = t >> 6, lane = t & 63;
  int wr = wave >> 1, wc = wave & 1;
  int lrow = lane & 15, lq = lane >> 4;     // lq in 0..3, k-octet
  const int row0 = bm * 128, col0 = bn * 128;

  // staging geometry: inst i covers rows i*32 + wave*8 + (lane>>3); octet (lane&7)^(r&7)
  int srow = wave * 8 + (lane >> 3);
  int soct = (lane & 7);

  f32x4 acc[4][4];
  #pragma unroll
  for (int m = 0; m < 4; ++m)
    #pragma unroll
    for (int n = 0; n < 4; ++n) acc[m][n] = f32x4{0.f, 0.f, 0.f, 0.f};

  for (int ks = 0; ks < Ec; ks += 64) {
    #pragma unroll
    for (int i = 0; i < 4; ++i) {
      int r = i * 32 + srow;
      int go = soct ^ (r & 7);
      GL2LDS(Xb + (row0 + r) * Ec + ks + go * 8, As + i * 2048 + wave * 512);
      GL2LDS(WT + (col0 + r) * Ec + ks + go * 8, Bs + i * 2048 + wave * 512);
    }
    __syncthreads();
    bf16x8 af[4][2], bfg[4][2];
    #pragma unroll
    for (int m = 0; m < 4; ++m) {
      int ra = wr * 64 + m * 16 + lrow;
      #pragma unroll
      for (int kk = 0; kk < 2; ++kk) {
        int o = kk * 4 + lq;
        af[m][kk] = *(const bf16x8*)(As + ra * 64 + ((o ^ (ra & 7)) << 3));
      }
    }
    #pragma unroll
    for (int n = 0; n < 4; ++n) {
      int rb = wc * 64 + n * 16 + lrow;
      #pragma unroll
      for (int kk = 0; kk < 2; ++kk) {
        int o = kk * 4 + lq;
        bfg[n][kk] = *(const bf16x8*)(Bs + rb * 64 + ((o ^ (rb & 7)) << 3));
      }
    }
    #pragma unroll
    for (int kk = 0; kk < 2; ++kk)
      #pragma unroll
      for (int m = 0; m < 4; ++m)
        #pragma unroll
        for (int n = 0; n < 4; ++n)
          acc[m][n] = __builtin_amdgcn_mfma_f32_16x16x32_bf16(af[m][kk], bfg[n][kk], acc[m][n], 0, 0, 0);
    __syncthreads();
  }
  int crow = lq * 4, ccol = lane & 15;
  #pragma unroll
  for (int m = 0; m < 4; ++m)
    #pragma unroll
    for (int n = 0; n < 4; ++n) {
      int col = col0 + wc * 64 + n * 16 + ccol;
      float bias = bb[col];
      #pragma unroll
      for (int j = 0; j < 4; ++j) {
        int row = row0 + wr * 64 + m * 16 + crow + j;
        QK[row * 1536 + col] = f2bf(acc[m][n][j] + bias);
      }
    }
}

// ---------- fused attention: per-(b,h,n-half) block, no inner barriers ----------
__global__ __launch_bounds__(256) void k_attn(const unsigned short* __restrict__ QK,
                                              const float* __restrict__ bias,
                                              const float* __restrict__ vfT,
                                              const float* __restrict__ delta,
                                              float* __restrict__ fpart) {
  __shared__ float vfl[256];
  int bi = blockIdx.x;
  int xcd = bi & 7, slot = bi >> 3;          // same b -> same XCD (L2 reuse of delta/QK)
  int b = xcd * 4 + slot / 24;
  int rem = slot % 24;
  int h = rem >> 1, nh = rem & 1;
  int t = threadIdx.x, wave = t >> 6, lane = t & 63;
  int lrow = lane & 15, lq = lane >> 4, lk8 = lq << 3;
  int n0w = nh * 128 + wave * 32;            // this wave's 32 query rows

  vfl[t] = vfT[(b * Hc + h) * Nc + t];
  __syncthreads();

  const unsigned short* Qbase = QK + (size_t)(b * Nc) * 1536 + h * 64;
  const unsigned short* Kbase = Qbase + 768;
  // hoisted Q fragments (B operand: rows = n)
  bf16x8 qf[2][2];
  #pragma unroll
  for (int nf = 0; nf < 2; ++nf)
    #pragma unroll
    for (int kk = 0; kk < 2; ++kk)
      qf[nf][kk] = *(const bf16x8*)(Qbase + (n0w + nf * 16 + lrow) * 1536 + kk * 32 + lk8);

  float s[2] = {0.f, 0.f}, f0[2] = {0.f, 0.f}, f1[2] = {0.f, 0.f}, f2[2] = {0.f, 0.f};
  const float* bptr = bias + (size_t)(b * Hc + h) * Nc * Nc;

  for (int mt = 0; mt < 4; ++mt) {
    int m0t = mt * 64;
    bf16x8 kf[4][2];
    #pragma unroll
    for (int mf = 0; mf < 4; ++mf)
      #pragma unroll
      for (int kk = 0; kk < 2; ++kk)
        kf[mf][kk] = *(const bf16x8*)(Kbase + (m0t + mf * 16 + lrow) * 1536 + kk * 32 + lk8);
    f32x4 acc[4][2];
    #pragma unroll
    for (int mf = 0; mf < 4; ++mf)
      #pragma unroll
      for (int nf = 0; nf < 2; ++nf) acc[mf][nf] = f32x4{0.f, 0.f, 0.f, 0.f};
    #pragma unroll
    for (int kk = 0; kk < 2; ++kk)
      #pragma unroll
      for (int mf = 0; mf < 4; ++mf)
        #pragma unroll
        for (int nf = 0; nf < 2; ++nf)
          acc[mf][nf] = __builtin_amdgcn_mfma_f32_16x16x32_bf16(kf[mf][kk], qf[nf][kk], acc[mf][nf], 0, 0, 0);
    // online combine: p = exp(score+bias); s += p; f_c += p*vf[m]*delta[n][m][c]
    #pragma unroll
    for (int mf = 0; mf < 4; ++mf) {
      int m0 = m0t + mf * 16 + lq * 4;       // 4 consecutive m (regs j=0..3)
      float4 vfv = *(const float4*)&vfl[m0];
      #pragma unroll
      for (int nf = 0; nf < 2; ++nf) {
        int n = n0w + nf * 16 + lrow;
        float4 bv = *(const float4*)(bptr + n * Nc + m0);
        const float* dp = delta + ((size_t)(b * Nc + n) * Nc + m0) * 3;
        float4 d0 = *(const float4*)(dp);
        float4 d1 = *(const float4*)(dp + 4);
        float4 d2 = *(const float4*)(dp + 8);
        float p0 = __expf(acc[mf][nf][0] + bv.x);
        float p1 = __expf(acc[mf][nf][1] + bv.y);
        float p2 = __expf(acc[mf][nf][2] + bv.z);
        float p3 = __expf(acc[mf][nf][3] + bv.w);
        s[nf] += (p0 + p1) + (p2 + p3);
        float w0 = p0 * vfv.x, w1 = p1 * vfv.y, w2 = p2 * vfv.z, w3 = p3 * vfv.w;
        f0[nf] += w0 * d0.x + w1 * d0.w + w2 * d1.z + w3 * d2.y;
        f1[nf] += w0 * d0.y + w1 * d1.x + w2 * d1.w + w3 * d2.z;
        f2[nf] += w0 * d0.z + w1 * d1.y + w2 * d2.x + w3 * d2.w;
      }
    }
  }
  // reduce the 4 m-partials (lane>>4 groups)
  #pragma unroll
  for (int nf = 0; nf < 2; ++nf) {
    s[nf]  += __shfl_xor(s[nf], 16);  s[nf]  += __shfl_xor(s[nf], 32);
    f0[nf] += __shfl_xor(f0[nf], 16); f0[nf] += __shfl_xor(f0[nf], 32);
    f1[nf] += __shfl_xor(f1[nf], 16); f1[nf] += __shfl_xor(f1[nf], 32);
    f2[nf] += __shfl_xor(f2[nf], 16); f2[nf] += __shfl_xor(f2[nf], 32);
  }
  if (lane < 16) {
    #pragma unroll
    for (int nf = 0; nf < 2; ++nf) {
      int n = n0w + nf * 16 + lane;
      float4 v; v.x = f0[nf]; v.y = f1[nf]; v.z = f2[nf]; v.w = s[nf];
      *(float4*)(fpart + ((size_t)(b * Hc + h) * Nc + n) * 4) = v;
    }
  }
}

// ---------- epilogue: force[b,n,c] = sum_h f_c/s ----------
__global__ __launch_bounds__(256) void k_force(const float* __restrict__ fpart,
                                               float* __restrict__ out) {
  int b = blockIdx.x, n = threadIdx.x;
  float a0 = 0.f, a1 = 0.f, a2 = 0.f;
  for (int h = 0; h < Hc; ++h) {
    float4 v = *(const float4*)(fpart + ((size_t)(b * Hc + h) * Nc + n) * 4);
    float inv = 1.f / v.w;
    a0 += v.x * inv; a1 += v.y * inv; a2 += v.z * inv;
  }
  float* o = out + (size_t)(b * Nc + n) * 3;
  o[0] = a0; o[1] = a1; o[2] = a2;
}

extern "C" void kernel_launch(void* const* d_in, const int* in_sizes, int n_in,
                              void* d_out, int out_size, void* d_ws, size_t ws_size,
                              hipStream_t stream) {
  const float* query = (const float*)d_in[0];
  const float* attn_bias = (const float*)d_in[1];
  const float* delta_pos = (const float*)d_in[2];
  const float* Wq = (const float*)d_in[3];
  const float* bq = (const float*)d_in[4];
  const float* Wk = (const float*)d_in[5];
  const float* bk = (const float*)d_in[6];
  const float* Wv = (const float*)d_in[7];
  const float* bv = (const float*)d_in[8];
  const float* wf = (const float*)d_in[9];
  float* out = (float*)d_out;

  char* ws = (char*)d_ws;
  unsigned short* WT  = (unsigned short*)(ws);              // 2,359,296 B
  unsigned short* QKb = (unsigned short*)(ws + 2359296);    // 25,165,824 B
  unsigned short* Xb  = (unsigned short*)(ws + 27525120);   // 12,582,912 B (dead after GEMM)
  float* fpart = (float*)(ws + 27525120);                   // 1,572,864 B (overlaps dead Xb)
  float* vfT = (float*)(ws + 40108032);                     // 393,216 B
  float* Wvf = (float*)(ws + 40501248);                     // 36,864 B
  float* bvf = (float*)(ws + 40538112);                     // 48 B
  float* bb  = (float*)(ws + 40538160);                     // 6,144 B

  k_trans<<<dim3(24, 24, 2), 256, 0, stream>>>(Wq, Wk, WT);
  k_build_wvf<<<36, 256, 0, stream>>>(Wv, bv, wf, bq, bk, Wvf, bvf, bb);
  k_vf<<<2048, 256, 0, stream>>>(query, Wvf, bvf, vfT, Xb);
  k_gemm_qk<<<dim3(64, 12), 256, 0, stream>>>(Xb, WT, bb, QKb);
  k_attn<<<768, 256, 0, stream>>>(QKb, attn_bias, vfT, delta_pos, fpart);
  k_force<<<Bc, 256, 0, stream>>>(fpart, out);
}

// Round 4
// 111.334 us; speedup vs baseline: 1.3773x; 1.3382x over previous
//
#include <hip/hip_runtime.h>
#include <hip/hip_bf16.h>

#define Bc 32
#define Nc 256
#define Ec 768
#define Hc 12
#define Dc 64

typedef __attribute__((ext_vector_type(8))) __bf16 bf16x8;
typedef __attribute__((ext_vector_type(8))) unsigned short u16x8;
typedef __attribute__((ext_vector_type(4))) float f32x4;

__device__ __forceinline__ unsigned short f2bf(float x) {
  union { float f; unsigned u; } v; v.f = x;
  unsigned r = v.u + 0x7fff + ((v.u >> 16) & 1);   // RNE
  return (unsigned short)(r >> 16);
}

#define GL2LDS(gp, lp) __builtin_amdgcn_global_load_lds( \
    (__attribute__((address_space(1))) void*)(gp),        \
    (__attribute__((address_space(3))) void*)(lp), 16, 0, 0)

// ---------- prep: WT[n][k] = bf16(scale*W[k][n]) via LDS tile transpose ----------
__global__ __launch_bounds__(256) void k_trans(const float* __restrict__ Wq,
                                               const float* __restrict__ Wk,
                                               unsigned short* __restrict__ WT) {
  __shared__ float tile[32][33];
  const float* W = blockIdx.z ? Wk : Wq;
  float scale = blockIdx.z ? 1.0f : 0.125f;
  int rowoff = blockIdx.z ? Ec : 0;
  int k0 = blockIdx.x * 32, n0 = blockIdx.y * 32;
  int r = threadIdx.x >> 5, c = threadIdx.x & 31;
  #pragma unroll
  for (int it = 0; it < 4; ++it)
    tile[r + 8 * it][c] = W[(k0 + r + 8 * it) * Ec + n0 + c];
  __syncthreads();
  #pragma unroll
  for (int it = 0; it < 4; ++it)
    WT[(rowoff + n0 + r + 8 * it) * Ec + k0 + c] = f2bf(scale * tile[c][r + 8 * it]);
}

// ---------- prep: Wvf[e][h] = sum_d Wv[e][h*64+d]*wf[.]; bvf; bb ----------
__global__ void k_build_wvf(const float* __restrict__ Wv, const float* __restrict__ bv,
                            const float* __restrict__ wf,
                            const float* __restrict__ bq, const float* __restrict__ bk,
                            float* __restrict__ Wvf, float* __restrict__ bvf,
                            float* __restrict__ bb) {
  int idx = blockIdx.x * 256 + threadIdx.x;
  if (idx < Ec * Hc) {
    int e = idx / Hc, h = idx % Hc;
    float s = 0.f;
    for (int d = 0; d < Dc; ++d) s += Wv[e * Ec + h * Dc + d] * wf[h * Dc + d];
    Wvf[idx] = s;
  }
  if (idx < Hc) {
    float s = 0.f;
    for (int d = 0; d < Dc; ++d) s += bv[idx * Dc + d] * wf[idx * Dc + d];
    bvf[idx] = s;
  }
  if (idx < 2 * Ec)
    bb[idx] = (idx < Ec) ? 0.125f * bq[idx] : bk[idx - Ec];
}

// ---------- vfT + fused query->bf16 conversion ----------
__global__ __launch_bounds__(256) void k_vf(const float* __restrict__ query,
                                            const float* __restrict__ Wvf,
                                            const float* __restrict__ bvf,
                                            float* __restrict__ vfT,
                                            unsigned short* __restrict__ Xb) {
  __shared__ float wl[Ec * 13];
  __shared__ float bl[Hc];
  for (int i = threadIdx.x; i < Ec * Hc; i += 256) {
    int e = i / Hc, h = i % Hc;
    wl[e * 13 + h] = Wvf[i];
  }
  if (threadIdx.x < Hc) bl[threadIdx.x] = bvf[threadIdx.x];
  __syncthreads();
  int warp = threadIdx.x >> 6, lane = threadIdx.x & 63;
  int r = blockIdx.x * 4 + warp;
  float q[12];
  #pragma unroll
  for (int i = 0; i < 12; ++i) q[i] = query[r * Ec + lane + 64 * i];
  #pragma unroll
  for (int i = 0; i < 12; ++i) Xb[r * Ec + lane + 64 * i] = f2bf(q[i]);
  int b = r >> 8, m = r & 255;
  for (int h = 0; h < Hc; ++h) {
    float s = 0.f;
    #pragma unroll
    for (int i = 0; i < 12; ++i) s += q[i] * wl[(lane + 64 * i) * 13 + h];
    #pragma unroll
    for (int off = 32; off; off >>= 1) s += __shfl_xor(s, off);
    if (lane == 0) vfT[(b * Hc + h) * Nc + m] = s + bl[h];
  }
}

// ---------- GEMM (m97 structure): QK[8192][1536] = Xb @ WT^T + bb ----------
__global__ __launch_bounds__(256) void k_gemm_qk(const unsigned short* __restrict__ Xb,
                                                 const unsigned short* __restrict__ WT,
                                                 const float* __restrict__ bb,
                                                 unsigned short* __restrict__ QK) {
  __shared__ unsigned short As[128 * 64];   // linear, XOR octet swizzle
  __shared__ unsigned short Bs[128 * 64];
  int bm = blockIdx.x, bn = blockIdx.y;
  int t = threadIdx.x;
  int wave = t >> 6, lane = t & 63;
  int wr = wave >> 1, wc = wave & 1;
  int lrow = lane & 15, lq = lane >> 4;
  const int row0 = bm * 128, col0 = bn * 128;

  int srow = wave * 8 + (lane >> 3);
  int soct = (lane & 7);

  f32x4 acc[4][4];
  #pragma unroll
  for (int m = 0; m < 4; ++m)
    #pragma unroll
    for (int n = 0; n < 4; ++n) acc[m][n] = f32x4{0.f, 0.f, 0.f, 0.f};

  for (int ks = 0; ks < Ec; ks += 64) {
    #pragma unroll
    for (int i = 0; i < 4; ++i) {
      int r = i * 32 + srow;
      int go = soct ^ (r & 7);
      GL2LDS(Xb + (row0 + r) * Ec + ks + go * 8, As + i * 2048 + wave * 512);
      GL2LDS(WT + (col0 + r) * Ec + ks + go * 8, Bs + i * 2048 + wave * 512);
    }
    __syncthreads();
    bf16x8 af[4][2], bfg[4][2];
    #pragma unroll
    for (int m = 0; m < 4; ++m) {
      int ra = wr * 64 + m * 16 + lrow;
      #pragma unroll
      for (int kk = 0; kk < 2; ++kk) {
        int o = kk * 4 + lq;
        af[m][kk] = *(const bf16x8*)(As + ra * 64 + ((o ^ (ra & 7)) << 3));
      }
    }
    #pragma unroll
    for (int n = 0; n < 4; ++n) {
      int rb = wc * 64 + n * 16 + lrow;
      #pragma unroll
      for (int kk = 0; kk < 2; ++kk) {
        int o = kk * 4 + lq;
        bfg[n][kk] = *(const bf16x8*)(Bs + rb * 64 + ((o ^ (rb & 7)) << 3));
      }
    }
    #pragma unroll
    for (int kk = 0; kk < 2; ++kk)
      #pragma unroll
      for (int m = 0; m < 4; ++m)
        #pragma unroll
        for (int n = 0; n < 4; ++n)
          acc[m][n] = __builtin_amdgcn_mfma_f32_16x16x32_bf16(af[m][kk], bfg[n][kk], acc[m][n], 0, 0, 0);
    __syncthreads();
  }
  int crow = lq * 4, ccol = lane & 15;
  #pragma unroll
  for (int m = 0; m < 4; ++m)
    #pragma unroll
    for (int n = 0; n < 4; ++n) {
      int col = col0 + wc * 64 + n * 16 + ccol;
      float bias = bb[col];
      #pragma unroll
      for (int j = 0; j < 4; ++j) {
        int row = row0 + wr * 64 + m * 16 + crow + j;
        QK[row * 1536 + col] = f2bf(acc[m][n][j] + bias);
      }
    }
}

// ---------- attention: block = (b, 16-row n-tile, 6-head group) ----------
// All global streams float4-coalesced; scores via MFMA -> swizzled LDS roundtrip.
__global__ __launch_bounds__(256, 4) void k_attn(const unsigned short* __restrict__ QK,
                                                 const float* __restrict__ bias,
                                                 const float* __restrict__ vfT,
                                                 const float* __restrict__ delta,
                                                 float* __restrict__ fpart) {
  __shared__ float S[16 * 256];     // [n][m], XOR-swizzled in 4-float chunks
  __shared__ float vfl[6][256];

  int bi = blockIdx.x;
  int xcd = bi & 7, slot = bi >> 3;            // same b -> same XCD
  int b = xcd * 4 + (slot >> 5);
  int rem = slot & 31;
  int nt = rem >> 1, hg = rem & 1;
  int n0 = nt * 16;

  int t = threadIdx.x, w = t >> 6, l = t & 63;
  int lq = l >> 4, lr = l & 15;

  #pragma unroll
  for (int i = 0; i < 6; ++i)
    vfl[i][t] = vfT[(b * Hc + hg * 6 + i) * Nc + t];

  float w_reg[4][4];
  #pragma unroll
  for (int p = 0; p < 4; ++p)
    #pragma unroll
    for (int i = 0; i < 4; ++i) w_reg[p][i] = 0.f;

  const unsigned short* Qbase = QK + (size_t)b * Nc * 1536;
  const unsigned short* Kbase = Qbase + 768;

  for (int hh = 0; hh < 6; ++hh) {
    int h = hg * 6 + hh;
    // prefetch bias (independent of MFMA -> latency hidden under compute)
    float4 bias4[4];
    const float* bp = bias + (size_t)(b * Hc + h) * Nc * Nc;
    #pragma unroll
    for (int p = 0; p < 4; ++p)
      bias4[p] = *(const float4*)(bp + (n0 + w * 4 + p) * Nc + l * 4);
    // Q fragments (B operand: cols = n)
    bf16x8 qf[2];
    #pragma unroll
    for (int kk = 0; kk < 2; ++kk)
      qf[kk] = *(const bf16x8*)(Qbase + (n0 + lr) * 1536 + h * 64 + kk * 32 + lq * 8);
    // scores: D[m][n], wave w owns m in [w*64, w*64+64)
    f32x4 acc[4];
    #pragma unroll
    for (int mf = 0; mf < 4; ++mf) acc[mf] = f32x4{0.f, 0.f, 0.f, 0.f};
    #pragma unroll
    for (int mf = 0; mf < 4; ++mf)
      #pragma unroll
      for (int kk = 0; kk < 2; ++kk) {
        bf16x8 af = *(const bf16x8*)(Kbase + (w * 64 + mf * 16 + lr) * 1536 + h * 64 + kk * 32 + lq * 8);
        acc[mf] = __builtin_amdgcn_mfma_f32_16x16x32_bf16(af, qf[kk], acc[mf], 0, 0, 0);
      }
    // write S[n][m] swizzled (write & read both at LDS bank floor)
    #pragma unroll
    for (int mf = 0; mf < 4; ++mf) {
      int m0 = w * 64 + mf * 16 + lq * 4;
      *(f32x4*)&S[lr * 256 + (m0 ^ ((lr & 7) << 2))] = acc[mf];
    }
    __syncthreads();
    // streaming passes: wave w, pass p -> row r = w*4+p; lane l -> m-chunk 4l
    #pragma unroll
    for (int p = 0; p < 4; ++p) {
      int r = w * 4 + p;
      float4 sv = *(const float4*)&S[r * 256 + ((l * 4) ^ ((r & 7) << 2))];
      float p0 = __expf(sv.x + bias4[p].x);
      float p1 = __expf(sv.y + bias4[p].y);
      float p2 = __expf(sv.z + bias4[p].z);
      float p3 = __expf(sv.w + bias4[p].w);
      float ssum = (p0 + p1) + (p2 + p3);
      #pragma unroll
      for (int off = 1; off < 64; off <<= 1) ssum += __shfl_xor(ssum, off);
      float inv = 1.f / ssum;
      float4 vf4 = *(const float4*)&vfl[hh][l * 4];
      w_reg[p][0] += p0 * inv * vf4.x;
      w_reg[p][1] += p1 * inv * vf4.y;
      w_reg[p][2] += p2 * inv * vf4.z;
      w_reg[p][3] += p3 * inv * vf4.w;
    }
    __syncthreads();
  }
  // delta contraction: coalesced (3072B contiguous per wave-row), read once
  #pragma unroll
  for (int p = 0; p < 4; ++p) {
    int r = w * 4 + p, n = n0 + r;
    const float* dp = delta + ((size_t)(b * Nc + n) * Nc + l * 4) * 3;
    float4 d0 = *(const float4*)(dp);
    float4 d1 = *(const float4*)(dp + 4);
    float4 d2 = *(const float4*)(dp + 8);
    float w0 = w_reg[p][0], w1 = w_reg[p][1], w2 = w_reg[p][2], w3 = w_reg[p][3];
    float f0 = w0 * d0.x + w1 * d0.w + w2 * d1.z + w3 * d2.y;
    float f1 = w0 * d0.y + w1 * d1.x + w2 * d1.w + w3 * d2.z;
    float f2 = w0 * d0.z + w1 * d1.y + w2 * d2.x + w3 * d2.w;
    #pragma unroll
    for (int off = 1; off < 64; off <<= 1) {
      f0 += __shfl_xor(f0, off);
      f1 += __shfl_xor(f1, off);
      f2 += __shfl_xor(f2, off);
    }
    if (l == 0) {
      float4 v; v.x = f0; v.y = f1; v.z = f2; v.w = 0.f;
      *(float4*)(fpart + ((size_t)(hg * Bc + b) * Nc + n) * 4) = v;
    }
  }
}

// ---------- epilogue: force = hg0 + hg1 ----------
__global__ __launch_bounds__(256) void k_force(const float* __restrict__ fpart,
                                               float* __restrict__ out) {
  int b = blockIdx.x, n = threadIdx.x;
  float4 a = *(const float4*)(fpart + ((size_t)(b)*Nc + n) * 4);
  float4 c = *(const float4*)(fpart + ((size_t)(Bc + b) * Nc + n) * 4);
  float* o = out + (size_t)(b * Nc + n) * 3;
  o[0] = a.x + c.x; o[1] = a.y + c.y; o[2] = a.z + c.z;
}

extern "C" void kernel_launch(void* const* d_in, const int* in_sizes, int n_in,
                              void* d_out, int out_size, void* d_ws, size_t ws_size,
                              hipStream_t stream) {
  const float* query = (const float*)d_in[0];
  const float* attn_bias = (const float*)d_in[1];
  const float* delta_pos = (const float*)d_in[2];
  const float* Wq = (const float*)d_in[3];
  const float* bq = (const float*)d_in[4];
  const float* Wk = (const float*)d_in[5];
  const float* bk = (const float*)d_in[6];
  const float* Wv = (const float*)d_in[7];
  const float* bv = (const float*)d_in[8];
  const float* wf = (const float*)d_in[9];
  float* out = (float*)d_out;

  char* ws = (char*)d_ws;
  unsigned short* WT  = (unsigned short*)(ws);              // 2,359,296 B
  unsigned short* QKb = (unsigned short*)(ws + 2359296);    // 25,165,824 B
  unsigned short* Xb  = (unsigned short*)(ws + 27525120);   // 12,582,912 B (dead after GEMM)
  float* fpart = (float*)(ws + 27525120);                   // 1,048,576 B (overlaps dead Xb)
  float* vfT = (float*)(ws + 40108032);                     // 393,216 B
  float* Wvf = (float*)(ws + 40501248);                     // 36,864 B
  float* bvf = (float*)(ws + 40538112);                     // 48 B
  float* bb  = (float*)(ws + 40538160);                     // 6,144 B

  k_trans<<<dim3(24, 24, 2), 256, 0, stream>>>(Wq, Wk, WT);
  k_build_wvf<<<36, 256, 0, stream>>>(Wv, bv, wf, bq, bk, Wvf, bvf, bb);
  k_vf<<<2048, 256, 0, stream>>>(query, Wvf, bvf, vfT, Xb);
  k_gemm_qk<<<dim3(64, 12), 256, 0, stream>>>(Xb, WT, bb, QKb);
  k_attn<<<1024, 256, 0, stream>>>(QKb, attn_bias, vfT, delta_pos, fpart);
  k_force<<<Bc, 256, 0, stream>>>(fpart, out);
}